// Round 4
// baseline (592.768 us; speedup 1.0000x reference)
//
#include <hip/hip_runtime.h>

// SNN forward, xs-path only. Intermediates channel-innermost: (N,H,W,T,C), T=40.
// Convs 2-7: MFMA 16x16x32 bf16, EXACT 3-way bf16 weight split. XCD-chunked
// grid swizzle + n-merge (L2-L4) to kill redundant weight HBM fetches.

constexpr int NT = 40;

typedef __attribute__((ext_vector_type(8))) short s16x8;
typedef __attribute__((ext_vector_type(4))) float f32x4;

__device__ __forceinline__ float bf2f(unsigned short u) {
    return __uint_as_float(((unsigned)u) << 16);
}

// ---------------- weight transpose for conv1: w[CO][R] -> wt[R][CO] ----------------
__global__ __launch_bounds__(256) void transpose_w(
    const float* __restrict__ w, float* __restrict__ wt, int CO, int R)
{
    __shared__ float tile[32][33];
    const int r0 = blockIdx.x * 32, c0 = blockIdx.y * 32;
    const int tx = threadIdx.x % 32, ty = threadIdx.x / 32;
#pragma unroll
    for (int k = 0; k < 4; k++) {
        const int co = c0 + ty + k * 8, r = r0 + tx;
        if (co < CO && r < R) tile[ty + k * 8][tx] = w[(size_t)co * R + r];
    }
    __syncthreads();
#pragma unroll
    for (int k = 0; k < 4; k++) {
        const int r = r0 + ty + k * 8, co = c0 + tx;
        if (r < R && co < CO) wt[(size_t)r * CO + co] = tile[tx][ty + k * 8];
    }
}

// ---------------- conv1: 3->128 @32x32 pad1, fp32 VALU, out channel-innermost ----------------
__global__ __launch_bounds__(320) void conv1_c(
    const float* __restrict__ in, const float* __restrict__ wt,
    const float* __restrict__ bias, float* __restrict__ out)
{
    __shared__ float xs_[27 * NT];
    __shared__ float wl[27 * 128];
    const int sp = blockIdx.x;
    const int ho = sp >> 5, wo = sp & 31;
    const int n = blockIdx.z;
    const int tid = threadIdx.x;
    const int tt = tid >> 5;
    const int cc = tid & 31;

    float4 acc[4];
#pragma unroll
    for (int j = 0; j < 4; j++) {
        const float bv = bias[cc * 4 + j];
        acc[j] = make_float4(bv, bv, bv, bv);
    }
    for (int u = tid; u < 270; u += 320) {
        const int r = u / 10, q = u % 10;
        const int cil = r / 9, k = r % 9;
        const int hi = ho + k / 3 - 1, wi = wo + k % 3 - 1;
        float4 v = make_float4(0.f, 0.f, 0.f, 0.f);
        if ((unsigned)hi < 32u && (unsigned)wi < 32u)
            v = *reinterpret_cast<const float4*>(
                in + ((size_t)((n * 3 + cil) * 1024 + hi * 32 + wi)) * NT + q * 4);
        *reinterpret_cast<float4*>(&xs_[r * NT + q * 4]) = v;
    }
    for (int u = tid; u < 864; u += 320) {
        const int r = u >> 5, j = u & 31;
        *reinterpret_cast<float4*>(&wl[r * 128 + j * 4]) =
            *reinterpret_cast<const float4*>(wt + r * 128 + j * 4);
    }
    __syncthreads();
#pragma unroll
    for (int r = 0; r < 27; ++r) {
        const float4 xv = *reinterpret_cast<const float4*>(&xs_[r * NT + tt * 4]);
        const float4 wv = *reinterpret_cast<const float4*>(&wl[r * 128 + cc * 4]);
        acc[0].x = fmaf(xv.x, wv.x, acc[0].x); acc[0].y = fmaf(xv.y, wv.x, acc[0].y);
        acc[0].z = fmaf(xv.z, wv.x, acc[0].z); acc[0].w = fmaf(xv.w, wv.x, acc[0].w);
        acc[1].x = fmaf(xv.x, wv.y, acc[1].x); acc[1].y = fmaf(xv.y, wv.y, acc[1].y);
        acc[1].z = fmaf(xv.z, wv.y, acc[1].z); acc[1].w = fmaf(xv.w, wv.y, acc[1].w);
        acc[2].x = fmaf(xv.x, wv.z, acc[2].x); acc[2].y = fmaf(xv.y, wv.z, acc[2].y);
        acc[2].z = fmaf(xv.z, wv.z, acc[2].z); acc[2].w = fmaf(xv.w, wv.z, acc[2].w);
        acc[3].x = fmaf(xv.x, wv.w, acc[3].x); acc[3].y = fmaf(xv.y, wv.w, acc[3].y);
        acc[3].z = fmaf(xv.z, wv.w, acc[3].z); acc[3].w = fmaf(xv.w, wv.w, acc[3].w);
    }
    const size_t base = (size_t)(n * 1024 + sp) * (NT * 128);
#pragma unroll
    for (int j = 0; j < 4; j++) {
        const int cb = cc * 4 + j;
        out[base + (tt * 4 + 0) * 128 + cb] = acc[j].x;
        out[base + (tt * 4 + 1) * 128 + cb] = acc[j].y;
        out[base + (tt * 4 + 2) * 128 + cb] = acc[j].z;
        out[base + (tt * 4 + 3) * 128 + cb] = acc[j].w;
    }
}

// ---------------- exact 3-way bf16 split: w[CO][CIN*9] -> {hi,mid,lo}[9][CO][CIN] ----------------
__global__ void split_w(const float* __restrict__ w,
                        unsigned short* __restrict__ hi, unsigned short* __restrict__ mid,
                        unsigned short* __restrict__ lo, int CO, int CIN_)
{
    const int idx = blockIdx.x * blockDim.x + threadIdx.x;
    if (idx >= CO * CIN_) return;
    const int co = idx / CIN_, ci = idx % CIN_;
    const float* src = w + ((size_t)co * CIN_ + ci) * 9;
#pragma unroll
    for (int k = 0; k < 9; ++k) {
        const float f = src[k];
        const unsigned u = __float_as_uint(f);
        const float fh = __uint_as_float(u & 0xFFFF0000u);
        const float r1 = f - fh;
        const unsigned u1 = __float_as_uint(r1);
        const float fm = __uint_as_float(u1 & 0xFFFF0000u);
        const float r2 = r1 - fm;
        const unsigned u2 = __float_as_uint(r2);
        const size_t dst = ((size_t)k * CO + co) * CIN_ + ci;
        hi[dst] = (unsigned short)(u >> 16);
        mid[dst] = (unsigned short)(u1 >> 16);
        lo[dst] = (unsigned short)(u2 >> 16);
    }
}

// ---------------- MFMA conv v2: XCD-chunked swizzle + optional n-merge ----------------
// spikes (N,H,W,T,CIN) bf16 -> out (N,HO,WO,T,COUT) fp32 (+split slabs)
template<int CIN_SEG, int COUT, int H, int W, int PAD, int BM, int BN,
         int NSPLIT, int NMERGE, int MINW, bool ZOUT>
__global__ __launch_bounds__(256, MINW) void conv_mfma2(
    const unsigned short* __restrict__ spk,
    const unsigned short* __restrict__ wlo, const unsigned short* __restrict__ wmid,
    const unsigned short* __restrict__ whi,
    const float* __restrict__ bias, float* __restrict__ out)
{
    constexpr int CIN = CIN_SEG * NSPLIT;
    constexpr int HO = PAD ? H : H - 2;
    constexpr int WO = PAD ? W : W - 2;
    constexpr int MROW = WO * NT;
    constexpr int MTILES = (MROW + BM - 1) / BM;
    constexpr int NX = HO * MTILES;
    constexpr int NY = COUT / BN;
    constexpr int NZ = (2 / NMERGE) * NSPLIT;
    constexpr int NB = NX * NY * NZ;
    static_assert(NB % 8 == 0, "grid must be divisible by 8 XCDs");
    constexpr int Q = NB / 8;
    constexpr int KC = CIN_SEG / 64;
    constexpr int WM = BM / 2;          // 2x2 wave layout, wave = WM x 32
    constexpr int MFRAG = WM / 16;
    __shared__ unsigned short smem[NMERGE * BM * 64 + 3 * BN * 64];

    // XCD-chunked swizzle: hw round-robins blockIdx%8 over XCDs; give each XCD
    // a contiguous chunk of the original id space (same weight panel together).
    const int g = blockIdx.x;
    const int orig = (g % 8) * Q + g / 8;
    const int x = orig % NX;
    const int rest = orig / NX;
    const int y  = ZOUT ? (rest % NY) : (rest / NZ);
    const int z  = ZOUT ? (rest / NY) : (rest % NZ);
    const int split = z % NSPLIT;
    const int nI    = z / NSPLIT;       // base n when NMERGE==1

    const int tid = threadIdx.x;
    const int lane = tid & 63;
    const int wv = tid >> 6;
    const int wm = wv >> 1;
    const int wn = wv & 1;
    const int lr = lane >> 4;
    const int lc = lane & 15;

    const int ho = x / MTILES;
    const int m0 = (x % MTILES) * BM;
    const int co0 = y * BN;

    f32x4 acc[NMERGE][MFRAG][2];
#pragma unroll
    for (int ni = 0; ni < NMERGE; ++ni)
#pragma unroll
        for (int mf = 0; mf < MFRAG; ++mf)
#pragma unroll
            for (int nf = 0; nf < 2; ++nf) {
                const float bv = (NSPLIT == 1 || split == 0)
                    ? bias[co0 + wn * 32 + nf * 16 + lc] : 0.f;
                acc[ni][mf][nf] = {bv, bv, bv, bv};
            }

    const unsigned short* wp[3] = {wlo, wmid, whi};

    for (int kh = 0; kh < 3; ++kh) {
        const int hirow = ho + kh - PAD;
        if (hirow < 0 || hirow >= H) continue;
        for (int kw = 0; kw < 3; ++kw) {
            const int kwp = kw - PAD;
            const int khw = kh * 3 + kw;
            for (int kc = 0; kc < KC; ++kc) {
                const int ci0 = split * CIN_SEG + kc * 64;
                // ---- stage A for NMERGE batch images ----
#pragma unroll
                for (int it = 0; it < NMERGE * BM / 32; ++it) {
                    const int idx = it * 256 + tid;
                    const int nn = idx / (BM * 8);
                    const int r = (idx >> 3) % BM, b = idx & 7;
                    const int n = (NMERGE == 2) ? nn : nI;
                    const int mg = m0 + r + kwp * NT;
                    s16x8 v = {0, 0, 0, 0, 0, 0, 0, 0};
                    if ((m0 + r) < MROW && mg >= 0 && mg < W * NT)
                        v = *(const s16x8*)(spk +
                            ((size_t)(n * H + hirow) * (W * NT) + mg) * CIN + ci0 + b * 8);
                    const int R = nn * BM + r;
                    *(s16x8*)&smem[R * 64 + ((b ^ (R & 7)) << 3)] = v;
                }
                // ---- stage B x3 splits ----
#pragma unroll
                for (int s = 0; s < 3; ++s) {
                    const unsigned short* wsrc = wp[s] + ((size_t)(khw * COUT + co0)) * CIN + ci0;
#pragma unroll
                    for (int it = 0; it < BN / 32; ++it) {
                        const int idx = it * 256 + tid;
                        const int r = idx >> 3, b = idx & 7;
                        const s16x8 v = *(const s16x8*)(wsrc + (size_t)r * CIN + b * 8);
                        *(s16x8*)&smem[NMERGE * BM * 64 + s * BN * 64 + r * 64 + ((b ^ (r & 7)) << 3)] = v;
                    }
                }
                __syncthreads();
#pragma unroll
                for (int kcs = 0; kcs < 2; ++kcs) {
                    const int c16 = kcs * 4 + lr;
                    s16x8 af[NMERGE][MFRAG];
#pragma unroll
                    for (int ni = 0; ni < NMERGE; ++ni)
#pragma unroll
                        for (int mf = 0; mf < MFRAG; ++mf) {
                            const int Ra = ni * BM + wm * WM + mf * 16 + lc;
                            af[ni][mf] = *(const s16x8*)&smem[Ra * 64 + ((c16 ^ (Ra & 7)) << 3)];
                        }
#pragma unroll
                    for (int s = 0; s < 3; ++s) {
#pragma unroll
                        for (int nf = 0; nf < 2; ++nf) {
                            const int Rb = wn * 32 + nf * 16 + lc;
                            const s16x8 bf_ = *(const s16x8*)&smem[NMERGE * BM * 64 + s * BN * 64 + Rb * 64 + ((c16 ^ (Rb & 7)) << 3)];
#pragma unroll
                            for (int ni = 0; ni < NMERGE; ++ni)
#pragma unroll
                                for (int mf = 0; mf < MFRAG; ++mf)
                                    acc[ni][mf][nf] = __builtin_amdgcn_mfma_f32_16x16x32_bf16(
                                        af[ni][mf], bf_, acc[ni][mf][nf], 0, 0, 0);
                        }
                    }
                }
                __syncthreads();
            }
        }
    }

    const size_t SLAB = (size_t)2 * HO * WO * NT * COUT;
#pragma unroll
    for (int ni = 0; ni < NMERGE; ++ni) {
        const int n = (NMERGE == 2) ? ni : nI;
        float* outp = out + (size_t)split * SLAB + (size_t)(n * HO + ho) * (WO * NT) * COUT;
#pragma unroll
        for (int mf = 0; mf < MFRAG; ++mf) {
            const int mbase = m0 + wm * WM + mf * 16;
            if (mbase >= MROW) continue;
#pragma unroll
            for (int nf = 0; nf < 2; ++nf) {
                const int col = co0 + wn * 32 + nf * 16 + lc;
#pragma unroll
                for (int j = 0; j < 4; ++j) {
                    const int m = mbase + lr * 4 + j;
                    outp[(size_t)m * COUT + col] = acc[ni][mf][nf][j];
                }
            }
        }
    }
}

// ---------------- IF scan, channel-innermost: fp32 conv-out -> bf16 spikes ----------------
__global__ void if_ci(const float* __restrict__ in, unsigned short* __restrict__ spk,
                      const float* __restrict__ thr, int C, int total)
{
    const int idx = blockIdx.x * blockDim.x + threadIdx.x;
    if (idx >= total) return;
    const int c = idx % C;
    const size_t base = (size_t)(idx / C) * NT * C + c;
    const float th = thr[c];
    float v = 0.f;
#pragma unroll
    for (int t = 0; t < NT; ++t) {
        const float x = in[base + (size_t)t * C];
        v += x;
        const float s = (v >= th) ? 1.f : 0.f;
        v -= s * th;
        spk[base + (size_t)t * C] = s != 0.f ? (unsigned short)0x3F80 : (unsigned short)0;
    }
}

// ---------------- pool 2x2 + IF, channel-innermost, bf16 spikes in/out ----------------
__global__ void pool_ci(const unsigned short* __restrict__ in, unsigned short* __restrict__ out,
                        const float* __restrict__ thr, int C, int HO, int WO, int total)
{
    const int idx = blockIdx.x * blockDim.x + threadIdx.x;
    if (idx >= total) return;
    const int c = idx % C;
    const int sp = idx / C;
    const int wo = sp % WO;
    const int ho = (sp / WO) % HO;
    const int n = sp / (WO * HO);
    const int H = 2 * HO, W = 2 * WO;
    const size_t b00 = (((size_t)(n * H + 2 * ho) * W + 2 * wo) * NT) * C + c;
    const size_t oB = (((size_t)(n * HO + ho) * WO + wo) * NT) * C + c;
    const size_t dW = (size_t)NT * C, dH = (size_t)W * NT * C;
    const float th = thr[c];
    float v = 0.f;
#pragma unroll
    for (int t = 0; t < NT; ++t) {
        const size_t o = (size_t)t * C;
        const float a = bf2f(in[b00 + o]) + bf2f(in[b00 + dW + o]) +
                        bf2f(in[b00 + dH + o]) + bf2f(in[b00 + dH + dW + o]);
        v += a * 0.25f;
        const float s = (v >= th) ? 1.f : 0.f;
        v -= s * th;
        out[oB + o] = s != 0.f ? (unsigned short)0x3F80 : (unsigned short)0;
    }
}

// ---------------- conv7 4-way partial reduce + IF -> bf16 spikes ----------------
__global__ void reduce_if7(const float* __restrict__ part, unsigned short* __restrict__ out,
                           const float* __restrict__ thr, int total)
{
    const int idx = blockIdx.x * blockDim.x + threadIdx.x;
    if (idx >= total) return;
    const int c = idx & 1023;
    const size_t base = (size_t)(idx >> 10) * NT * 1024 + c;
    const size_t SL = 327680;
    const float th = thr[c];
    float v = 0.f;
#pragma unroll
    for (int t = 0; t < NT; ++t) {
        const size_t o = (size_t)t * 1024;
        const float x = part[base + o] + part[SL + base + o] +
                        part[2 * SL + base + o] + part[3 * SL + base + o];
        v += x;
        const float s = (v >= th) ? 1.f : 0.f;
        v -= s * th;
        out[base + o] = s != 0.f ? (unsigned short)0x3F80 : (unsigned short)0;
    }
}

// ---------------- classifier: bf16 spikes (N,T,1024) ----------------
__global__ __launch_bounds__(1024) void classifier_ci(
    const unsigned short* __restrict__ s, const float* __restrict__ wc,
    const float* __restrict__ bc, float* __restrict__ out)
{
    __shared__ float cnt[2][1024];
    const int c = threadIdx.x;
    for (int n = 0; n < 2; n++) {
        float sum = 0.f;
#pragma unroll
        for (int t = 0; t < NT; ++t) sum += bf2f(s[(size_t)(n * NT + t) * 1024 + c]);
        cnt[n][c] = sum;
    }
    __syncthreads();
    if (threadIdx.x < 20) {
        const int n = threadIdx.x / 10, o = threadIdx.x % 10;
        float a = 0.f;
        for (int k = 0; k < 1024; k++) a += cnt[n][k] * wc[o * 1024 + k];
        out[n * 10 + o] = a * (1.f / 40.f) + bc[o];
    }
}

extern "C" void kernel_launch(void* const* d_in, const int* in_sizes, int n_in,
                              void* d_out, int out_size, void* d_ws, size_t ws_size,
                              hipStream_t stream)
{
    const float* x   = (const float*)d_in[0];
    const float* w1  = (const float*)d_in[1];  const float* b1 = (const float*)d_in[2];
    const float* w2  = (const float*)d_in[3];  const float* b2 = (const float*)d_in[4];
    const float* w3  = (const float*)d_in[5];  const float* b3 = (const float*)d_in[6];
    const float* w4  = (const float*)d_in[7];  const float* b4 = (const float*)d_in[8];
    const float* w5  = (const float*)d_in[9];  const float* b5 = (const float*)d_in[10];
    const float* w6  = (const float*)d_in[11]; const float* b6 = (const float*)d_in[12];
    const float* w7  = (const float*)d_in[13]; const float* b7 = (const float*)d_in[14];
    const float* wc  = (const float*)d_in[15]; const float* bc = (const float*)d_in[16];
    const float* thr1 = (const float*)d_in[17];
    const float* thr2 = (const float*)d_in[18];
    const float* p1   = (const float*)d_in[19];
    const float* thr3 = (const float*)d_in[20];
    const float* thr4 = (const float*)d_in[21];
    const float* p2   = (const float*)d_in[22];
    const float* thr5 = (const float*)d_in[23];
    const float* thr6 = (const float*)d_in[24];
    const float* p3   = (const float*)d_in[25];
    const float* thr7 = (const float*)d_in[26];
    const float* p4   = (const float*)d_in[27];

    char* W0 = (char*)d_ws;
    float* OUT = (float*)W0;                                   // 44 MB fp32 conv-out (+conv7 slabs)
    unsigned short* SPKA = (unsigned short*)(W0 + ((size_t)44 << 20));  // 22 MB
    unsigned short* SPKB = (unsigned short*)(W0 + ((size_t)66 << 20));  // 22 MB
    unsigned short* WH   = (unsigned short*)(W0 + ((size_t)88 << 20));  // 3 x 9.44 MB
    unsigned short* WMID = WH + 4718592;
    unsigned short* WLO  = WH + 2 * 4718592;
    float* WT1 = (float*)(W0 + ((size_t)118 << 20));           // 13.8 KB
    float* O = (float*)d_out;

    // conv1 (fp32) + IF
    transpose_w<<<dim3(1, 4), 256, 0, stream>>>(w1, WT1, 128, 27);
    conv1_c<<<dim3(1024, 1, 2), 320, 0, stream>>>(x, WT1, b1, OUT);
    if_ci<<<1024, 256, 0, stream>>>(OUT, SPKA, thr1, 128, 262144);

    // L2: BM128 BN64 n-merge, NB = 320*2*1 = 640
    split_w<<<64, 256, 0, stream>>>(w2, WH, WMID, WLO, 128, 128);
    conv_mfma2<128, 128, 32, 32, 1, 128, 64, 1, 2, 2, true>
        <<<640, 256, 0, stream>>>(SPKA, WLO, WMID, WH, b2, OUT);
    if_ci<<<1024, 256, 0, stream>>>(OUT, SPKB, thr2, 128, 262144);
    pool_ci<<<256, 256, 0, stream>>>(SPKB, SPKA, p1, 128, 16, 16, 65536);

    // L3: NB = 80*4*1 = 320
    split_w<<<128, 256, 0, stream>>>(w3, WH, WMID, WLO, 256, 128);
    conv_mfma2<128, 256, 16, 16, 1, 128, 64, 1, 2, 2, true>
        <<<320, 256, 0, stream>>>(SPKA, WLO, WMID, WH, b3, OUT);
    if_ci<<<512, 256, 0, stream>>>(OUT, SPKB, thr3, 256, 131072);

    // L4: NB = 80*4*1 = 320
    split_w<<<256, 256, 0, stream>>>(w4, WH, WMID, WLO, 256, 256);
    conv_mfma2<256, 256, 16, 16, 1, 128, 64, 1, 2, 2, true>
        <<<320, 256, 0, stream>>>(SPKB, WLO, WMID, WH, b4, OUT);
    if_ci<<<512, 256, 0, stream>>>(OUT, SPKA, thr4, 256, 131072);
    pool_ci<<<128, 256, 0, stream>>>(SPKA, SPKB, p2, 256, 8, 8, 32768);

    // L5: BM64 BN64 no-merge z-outer, NB = 40*8*2 = 640
    split_w<<<512, 256, 0, stream>>>(w5, WH, WMID, WLO, 512, 256);
    conv_mfma2<256, 512, 8, 8, 1, 64, 64, 1, 1, 4, true>
        <<<640, 256, 0, stream>>>(SPKB, WLO, WMID, WH, b5, OUT);
    if_ci<<<256, 256, 0, stream>>>(OUT, SPKA, thr5, 512, 65536);

    // L6: NB = 40*8*2 = 640
    split_w<<<1024, 256, 0, stream>>>(w6, WH, WMID, WLO, 512, 512);
    conv_mfma2<512, 512, 8, 8, 1, 64, 64, 1, 1, 4, true>
        <<<640, 256, 0, stream>>>(SPKA, WLO, WMID, WH, b6, OUT);
    if_ci<<<256, 256, 0, stream>>>(OUT, SPKB, thr6, 512, 65536);
    pool_ci<<<64, 256, 0, stream>>>(SPKB, SPKA, p3, 512, 4, 4, 16384);

    // L7: K-split x4, BN64, y-outer, NB = 4*16*8 = 512
    split_w<<<2048, 256, 0, stream>>>(w7, WH, WMID, WLO, 1024, 512);
    conv_mfma2<128, 1024, 4, 4, 0, 64, 64, 4, 1, 4, false>
        <<<512, 256, 0, stream>>>(SPKA, WLO, WMID, WH, b7, OUT);
    reduce_if7<<<32, 256, 0, stream>>>(OUT, SPKB, thr7, 8192);
    pool_ci<<<8, 256, 0, stream>>>(SPKB, SPKA, p4, 1024, 1, 1, 2048);

    // classifier
    classifier_ci<<<1, 1024, 0, stream>>>(SPKA, wc, bc, O);
}